// Round 13
// baseline (152.887 us; speedup 1.0000x reference)
//
#include <hip/hip_runtime.h>
#include <hip/hip_bf16.h>

#define T_  256
#define NN_ 2048
#define RSC 0.02209708691207961f   // 1/sqrt(2048)

typedef short bf16x8 __attribute__((ext_vector_type(8)));
typedef float f32x4  __attribute__((ext_vector_type(4)));
typedef unsigned u32x4 __attribute__((ext_vector_type(4)));

__device__ __forceinline__ unsigned short f2bf(float x) {
    union { float f; unsigned u; } v; v.f = x;
    unsigned r = v.u + 0x7fffu + ((v.u >> 16) & 1u);   // RTNE, finite inputs
    return (unsigned short)(r >> 16);
}
__device__ __forceinline__ float bflo(unsigned w) {
    union { unsigned u; float f; } v; v.u = w << 16; return v.f;
}
__device__ __forceinline__ float bfhi(unsigned w) {
    union { unsigned u; float f; } v; v.u = w & 0xffff0000u; return v.f;
}
__device__ __forceinline__ unsigned pkbf(float lo, float hi) {
    union { __hip_bfloat16 h; unsigned short s; } a, b;
    a.h = __float2bfloat16(lo);
    b.h = __float2bfloat16(hi);
    return (unsigned)a.s | ((unsigned)b.s << 16);
}
__device__ __forceinline__ void gld16(const void* g, void* l) {
    __builtin_amdgcn_global_load_lds(
        (const __attribute__((address_space(1))) unsigned int*)g,
        (__attribute__((address_space(3))) unsigned int*)l, 16, 0, 0);
}

// ---------------------------------------------------------------------------
// prep: fused  (a) vtrans V fp32 -> Vt bf16 [b][d][s]   (blocks 0..255)
//              (b) build cs table (global, dense [p][512]) (blocks 256..287)
// cs[p*512+f] = packed bf16 (cos,sin) of 2*pi*frac(p * 10000^(-f/512)).
// Token t, channel n: p = (bit9(n)? t&15 : t>>4), f = n & 511.
// ---------------------------------------------------------------------------
__global__ void prep(const float* __restrict__ V, unsigned short* __restrict__ Vt,
                     unsigned* __restrict__ cs) {
    const int tid = threadIdx.x;
    if (blockIdx.x >= 256) {
        int idx = (blockIdx.x - 256) * 256 + tid;     // 8192 entries
        int p = idx >> 9, f = idx & 511;
        float inv = powf(10000.0f, -(float)f * (1.0f / 512.0f));
        float ph  = (float)p * inv;
        float ang = (ph - floorf(ph)) * 6.28318530717958647692f;
        float s, c;
        sincosf(ang, &s, &c);
        cs[idx] = pkbf(c, s);
        return;
    }
    __shared__ unsigned short Tl[64 * 72];
    const int b  = blockIdx.x >> 4;
    const int s0 = ((blockIdx.x >> 2) & 3) << 6;
    const int d0 = (blockIdx.x & 3) << 6;
    const float* Vb = V + (size_t)b * 65536;
#pragma unroll
    for (int u = 0; u < 4; u++) {
        int lin = u * 256 + tid;
        int srow = lin >> 4, c4 = (lin & 15) << 2;
        float4 v = *(const float4*)(Vb + (size_t)(s0 + srow) * 256 + d0 + c4);
        Tl[(c4 + 0) * 72 + srow] = f2bf(v.x);
        Tl[(c4 + 1) * 72 + srow] = f2bf(v.y);
        Tl[(c4 + 2) * 72 + srow] = f2bf(v.z);
        Tl[(c4 + 3) * 72 + srow] = f2bf(v.w);
    }
    __syncthreads();
    unsigned short* Vtb = Vt + (size_t)b * 65536;
#pragma unroll
    for (int u = 0; u < 2; u++) {
        int lin = u * 256 + tid;
        int drow = lin >> 3, sc8 = (lin & 7) << 3;
        *(uint4*)(Vtb + (size_t)(d0 + drow) * 256 + s0 + sc8) =
            *(const uint4*)(&Tl[drow * 72 + sc8]);
    }
}

// ---------------------------------------------------------------------------
// gemm1f: scores = RoPE(Q).RoPE(K)^T / sqrt(N)  -- FUSED.
// Tile 128x128, 512 threads (8 waves, 2x4), BK=32, 256 blocks = 1/CU.
// - raw fp32 Q/K staged via global_load_lds (linear LDS dest, XOR-swizzled
//   GLOBAL source per G21; frag ds_reads conflict-free-ish 2-way).
// - RoPE applied in registers at fragment-read time (fp32 ds_read -> rotate
//   -> bf16 pack -> MFMA).  No bf16 LDS tile, ONE compute phase per k-step.
// - cs table (16p x 512f, stride 516 dwords) in LDS, loaded once.
//   w = bit9(channel) is k-step-uniform; w=0 -> p lane-uniform (broadcast),
//   w=1 -> p = lr (stride-516 spreads banks, 2-way max).
// - counted vmcnt(4): next slab's 4 glds issued before waiting current's.
// FIX R12: phase position must use GLOBAL token (ti/si + local row) -- the
// R11 version used tile-local rows, corrupting all ti=128 / si=128 quadrants.
// Also: final vmcnt(0) drain so late LDS-DMA can't land after endpgm.
// ---------------------------------------------------------------------------
__launch_bounds__(512)
__global__ void gemm1f(const float* __restrict__ Q, const float* __restrict__ K,
                       const unsigned* __restrict__ cs,
                       unsigned short* __restrict__ scores) {
    __shared__ __align__(16) float rawA[2][128 * 32];   // 32 KB
    __shared__ __align__(16) float rawB[2][128 * 32];   // 32 KB
    __shared__ __align__(16) unsigned csl[16 * 516];    // 33 KB

    const int tid = threadIdx.x;
    const int bh  = blockIdx.x & 63;          // bh%8 fixed per XCD
    const int qd  = blockIdx.x >> 6;          // 0..3 quadrant
    const int ti  = (qd >> 1) << 7;           // Q rows 0/128
    const int si  = (qd & 1) << 7;            // K rows 0/128

    const float* Qb = Q + (size_t)bh * (T_ * NN_);
    const float* Kb = K + (size_t)bh * (T_ * NN_);

    // ---- staging geometry: 2 A-units + 2 B-units per thread (16B each).
    const float* srcA[2]; int ldsA[2];
    const float* srcB[2]; int ldsB[2];
#pragma unroll
    for (int u = 0; u < 2; u++) {
        int lin = u * 512 + tid;               // 0..1023
        int row = lin >> 3, d = lin & 7;
        int sg  = (d ^ (row & 7)) << 2;        // swizzled source col (floats)
        srcA[u] = Qb + (size_t)(ti + row) * NN_ + sg;
        srcB[u] = Kb + (size_t)(si + row) * NN_ + sg;
        ldsA[u] = lin << 2;                    // float offset = 16B * lin
        ldsB[u] = lin << 2;
    }
    // cs staging: 4 units/thread; dest [p][516] padded, wave-uniform-safe
    const unsigned* csrc[4]; int cdst[4];
#pragma unroll
    for (int u = 0; u < 4; u++) {
        int cu = u * 512 + tid;                // 0..2047
        int p = cu >> 7, fg = cu & 127;
        csrc[u] = cs + (p << 9) + (fg << 2);
        cdst[u] = p * 516 + (fg << 2);
    }

    // ---- fragment geometry
    const int wv = tid >> 6, lane = tid & 63;
    const int lr = lane & 15, lg = lane >> 4;
    const int m0 = (wv >> 2) * 64;             // 0,64
    const int n0 = (wv & 3) * 32;              // 0..96

    int offA0[4], offA1[4], pAh[4], pAw[4];
#pragma unroll
    for (int mi = 0; mi < 4; mi++) {
        int row = m0 + mi * 16 + lr;           // tile-local (LDS addressing)
        int gr  = ti + row;                    // GLOBAL token (phase index)
        offA0[mi] = row * 32 + ((( 2 * lg    ) ^ (row & 7)) << 2);
        offA1[mi] = row * 32 + (((2 * lg + 1) ^ (row & 7)) << 2);
        pAh[mi] = gr >> 4;  pAw[mi] = gr & 15;
    }
    int offB0[2], offB1[2], pBh[2], pBw[2];
#pragma unroll
    for (int ni = 0; ni < 2; ni++) {
        int row = n0 + ni * 16 + lr;
        int gr  = si + row;                    // GLOBAL token (phase index)
        offB0[ni] = row * 32 + ((( 2 * lg    ) ^ (row & 7)) << 2);
        offB1[ni] = row * 32 + (((2 * lg + 1) ^ (row & 7)) << 2);
        pBh[ni] = gr >> 4;  pBw[ni] = gr & 15;
    }

    f32x4 acc[4][2];
#pragma unroll
    for (int i = 0; i < 4; i++)
#pragma unroll
        for (int j = 0; j < 2; j++) acc[i][j] = (f32x4){0.f, 0.f, 0.f, 0.f};

    // rotate 8 fp32 channels -> bf16x8 fragment, cs from LDS
    auto FRAG = [&](const float* rb, int o0, int o1, int p, int fb) -> bf16x8 {
        float4 x0 = *(const float4*)(rb + o0);
        float4 x1 = *(const float4*)(rb + o1);
        const unsigned* ce = &csl[p * 516 + fb];
        uint4 e0 = *(const uint4*)(ce);
        uint4 e1 = *(const uint4*)(ce + 4);
        union { u32x4 u; bf16x8 h; } o;
        o.u[0] = pkbf(x0.x * bflo(e0.x) - x0.y * bfhi(e0.x),
                      x0.y * bflo(e0.y) + x0.x * bfhi(e0.y));
        o.u[1] = pkbf(x0.z * bflo(e0.z) - x0.w * bfhi(e0.z),
                      x0.w * bflo(e0.w) + x0.z * bfhi(e0.w));
        o.u[2] = pkbf(x1.x * bflo(e1.x) - x1.y * bfhi(e1.x),
                      x1.y * bflo(e1.y) + x1.x * bfhi(e1.y));
        o.u[3] = pkbf(x1.z * bflo(e1.z) - x1.w * bfhi(e1.z),
                      x1.w * bflo(e1.w) + x1.z * bfhi(e1.w));
        return o.h;
    };

    // ---- prologue: cs (once) + slab 0 -> buf0
#pragma unroll
    for (int u = 0; u < 4; u++) gld16(csrc[u], &csl[cdst[u]]);
#pragma unroll
    for (int u = 0; u < 2; u++) {
        gld16(srcA[u], &rawA[0][ldsA[u]]);
        gld16(srcB[u], &rawB[0][ldsB[u]]);
    }
    asm volatile("s_waitcnt vmcnt(0)" ::: "memory");
    __builtin_amdgcn_s_barrier();
    asm volatile("" ::: "memory");

    // ---- main loop: 64 k-steps of 32 channels
#pragma unroll 1
    for (int k = 0; k < 64; ++k) {
        const int cur = k & 1;
        const int kn  = (k < 63) ? (k + 1) : 63;   // clamp keeps vmcnt count fixed
#pragma unroll
        for (int u = 0; u < 2; u++) {
            gld16(srcA[u] + (kn << 5), &rawA[cur ^ 1][ldsA[u]]);
            gld16(srcB[u] + (kn << 5), &rawB[cur ^ 1][ldsB[u]]);
        }
        asm volatile("s_waitcnt vmcnt(4)" ::: "memory");   // current slab done
        __builtin_amdgcn_s_barrier();
        asm volatile("" ::: "memory");

        const int k0 = k << 5;
        const int fk = k0 & 511;
        const int w  = (k0 >> 9) & 1;              // k-step-uniform h/w select
        const int fb = fk + lg * 8;

        bf16x8 afr[4], bfr[2];
#pragma unroll
        for (int mi = 0; mi < 4; mi++)
            afr[mi] = FRAG(&rawA[cur][0], offA0[mi], offA1[mi],
                           w ? pAw[mi] : pAh[mi], fb);
#pragma unroll
        for (int ni = 0; ni < 2; ni++)
            bfr[ni] = FRAG(&rawB[cur][0], offB0[ni], offB1[ni],
                           w ? pBw[ni] : pBh[ni], fb);

        __builtin_amdgcn_s_setprio(1);
#pragma unroll
        for (int mi = 0; mi < 4; mi++)
#pragma unroll
            for (int ni = 0; ni < 2; ni++)
                acc[mi][ni] = __builtin_amdgcn_mfma_f32_16x16x32_bf16(
                    afr[mi], bfr[ni], acc[mi][ni], 0, 0, 0);
        __builtin_amdgcn_s_setprio(0);

        asm volatile("s_waitcnt lgkmcnt(0)" ::: "memory");  // my LDS reads done
        __builtin_amdgcn_s_barrier();                       // before buf reuse
        asm volatile("" ::: "memory");
    }

    // drain the tail prefetch so no LDS-DMA lands after this workgroup exits
    asm volatile("s_waitcnt vmcnt(0)" ::: "memory");

    // ---- epilogue: scale, cast bf16, store scores[bh][t][s]
    unsigned short* sb = scores + (size_t)bh * (T_ * T_);
#pragma unroll
    for (int mi = 0; mi < 4; mi++) {
        int tr = ti + m0 + mi * 16 + lg * 4;
#pragma unroll
        for (int ni = 0; ni < 2; ni++) {
            int sc = si + n0 + ni * 16 + lr;
#pragma unroll
            for (int r = 0; r < 4; r++)
                sb[(size_t)(tr + r) * 256 + sc] = f2bf(acc[mi][ni][r] * RSC);
        }
    }
}

// ---------------------------------------------------------------------------
// gemm2b: out = scores @ V via Vt bf16 [d][s].  glds skeleton, K=256.
// NT stores for `out` (written once, never read).
// ---------------------------------------------------------------------------
__launch_bounds__(256)
__global__ void gemm2b(const unsigned short* __restrict__ scores,
                       const unsigned short* __restrict__ Vt, float* __restrict__ out) {
    __shared__ __align__(16) unsigned short A[128 * 64];
    __shared__ __align__(16) unsigned short Bt[64 * 64];

    const int tid  = threadIdx.x;
    const int bh   = blockIdx.x & 63;
    const int b    = bh >> 2;
    const int tile = blockIdx.x >> 6;          // 0..7
    const int ti = (tile >> 2) << 7;           // 0,128   (t rows)
    const int d0 = (tile & 3) << 6;            // 0..192  (d cols)

    const unsigned short* Sb  = scores + (size_t)bh * 65536;
    const unsigned short* Vtb = Vt + (size_t)b * 65536;

    const unsigned short* srcA[4]; unsigned short* dstA[4];
    const unsigned short* srcB[2]; unsigned short* dstB[2];
#pragma unroll
    for (int u = 0; u < 4; u++) {
        int lin = u * 256 + tid;
        int row = lin >> 3, cu = lin & 7;
        int scol = cu ^ (row & 7);
        srcA[u] = Sb + (size_t)(ti + row) * 256 + scol * 8;
        dstA[u] = &A[lin * 8];
    }
#pragma unroll
    for (int u = 0; u < 2; u++) {
        int lin = u * 256 + tid;
        int row = lin >> 3, cu = lin & 7;
        int scol = cu ^ (row & 7);
        srcB[u] = Vtb + (size_t)(d0 + row) * 256 + scol * 8;
        dstB[u] = &Bt[lin * 8];
    }

    const int wv = tid >> 6, lane = tid & 63;
    const int lr = lane & 15, lg = lane >> 4;
    const int m0 = (wv >> 1) * 64;
    const int n0 = (wv & 1) * 32;

    f32x4 acc[4][2];
#pragma unroll
    for (int i = 0; i < 4; i++)
#pragma unroll
        for (int j = 0; j < 2; j++) acc[i][j] = (f32x4){0.f, 0.f, 0.f, 0.f};

    for (int k0 = 0; k0 < 256; k0 += 64) {
#pragma unroll
        for (int u = 0; u < 4; u++) gld16(srcA[u] + k0, dstA[u]);
#pragma unroll
        for (int u = 0; u < 2; u++) gld16(srcB[u] + k0, dstB[u]);
        __syncthreads();

#pragma unroll
        for (int kk = 0; kk < 64; kk += 32) {
            bf16x8 af[4], bfr[2];
#pragma unroll
            for (int mi = 0; mi < 4; mi++) {
                int row = m0 + mi * 16 + lr;
                int c   = (kk >> 3) + lg;
                af[mi] = *(const bf16x8*)(&A[row * 64 + ((c ^ (row & 7)) << 3)]);
            }
#pragma unroll
            for (int ni = 0; ni < 2; ni++) {
                int row = n0 + ni * 16 + lr;
                int c   = (kk >> 3) + lg;
                bfr[ni] = *(const bf16x8*)(&Bt[row * 64 + ((c ^ (row & 7)) << 3)]);
            }
#pragma unroll
            for (int mi = 0; mi < 4; mi++)
#pragma unroll
                for (int ni = 0; ni < 2; ni++)
                    acc[mi][ni] = __builtin_amdgcn_mfma_f32_16x16x32_bf16(
                        af[mi], bfr[ni], acc[mi][ni], 0, 0, 0);
        }
        __syncthreads();
    }

    float* ob = out + (size_t)bh * 65536;
#pragma unroll
    for (int mi = 0; mi < 4; mi++) {
        int tr = ti + m0 + mi * 16 + lg * 4;
#pragma unroll
        for (int ni = 0; ni < 2; ni++) {
            int dc = d0 + n0 + ni * 16 + lr;
#pragma unroll
            for (int r = 0; r < 4; r++)
                __builtin_nontemporal_store(acc[mi][ni][r],
                                            ob + (size_t)(tr + r) * 256 + dc);
        }
    }
}

// ---------------------------------------------------------------------------
extern "C" void kernel_launch(void* const* d_in, const int* in_sizes, int n_in,
                              void* d_out, int out_size, void* d_ws, size_t ws_size,
                              hipStream_t stream) {
    const float* Q = (const float*)d_in[0];
    const float* K = (const float*)d_in[1];
    const float* V = (const float*)d_in[2];
    float* out = (float*)d_out;

    unsigned* cs = (unsigned*)d_ws;                                        // 32 KB
    unsigned short* scores = (unsigned short*)((char*)d_ws + 32768);       // 8 MB
    unsigned short* Vt = (unsigned short*)((char*)d_ws + 32768 + 8388608); // 2 MB

    prep<<<dim3(288), dim3(256), 0, stream>>>(V, Vt, cs);
    gemm1f<<<dim3(256), dim3(512), 0, stream>>>(Q, K, cs, scores);
    gemm2b<<<dim3(512), dim3(256), 0, stream>>>(scores, Vt, out);
}